// Round 1
// baseline (2125.045 us; speedup 1.0000x reference)
//
#include <hip/hip_runtime.h>
#include <math.h>

#define TT 4096
#define DD 1024
#define HH 768
#define NE 23
#define NG 24          // 23 experts + shared as group 23
#define BM 64
#define BN 128
#define BK 32
#define MAXTILES 280   // sum ceil(n_e/64) <= 215, + 64 shared tiles = 279

// ws layout in 4-byte words
#define WS_COUNTS 0
#define WS_PSUM   32
#define WS_OFFS   64
#define WS_TOFFS  96
#define WS_CURS   136
#define WS_TOTAL  168
#define WS_TOKE   256
#define WS_TOKW   (WS_TOKE + TT*3)            // 12544
#define WS_LTOK   (WS_TOKW + TT*3)            // 24832
#define WS_LW     (WS_LTOK + TT*4)            // 41216 (12288 expert + 4096 shared)
#define WS_H      65536                        // H buffer: 16384*768 f32

__global__ __launch_bounds__(256) void k_gate(
    const float* __restrict__ x, const float* __restrict__ gW,
    const float* __restrict__ gb, const float* __restrict__ bias,
    int* __restrict__ counts, float* __restrict__ Psum,
    int* __restrict__ tokE, float* __restrict__ tokW)
{
    __shared__ float xs[4][DD];
    __shared__ float gv[4][NE];
    const int tid = threadIdx.x;
    const int t0 = blockIdx.x * 4;
    {   // stage 4 tokens of x
        const float4* src = (const float4*)(x + (size_t)t0 * DD);
        float4* dst = (float4*)&xs[0][0];
        #pragma unroll
        for (int i = 0; i < 4; i++) dst[tid + 256 * i] = src[tid + 256 * i];
    }
    __syncthreads();
    const int w = tid >> 6, l = tid & 63;
    const int t = t0 + w;
    if (l < NE) {
        float s0 = 0.f, s1 = 0.f, s2 = 0.f, s3 = 0.f;
        const float* xw = xs[w];
        for (int d = 0; d < DD; d += 4) {
            s0 = fmaf(xw[d + 0], gW[(d + 0) * NE + l], s0);
            s1 = fmaf(xw[d + 1], gW[(d + 1) * NE + l], s1);
            s2 = fmaf(xw[d + 2], gW[(d + 2) * NE + l], s2);
            s3 = fmaf(xw[d + 3], gW[(d + 3) * NE + l], s3);
        }
        float s = (s0 + s1) + (s2 + s3) + gb[l];
        gv[w][l] = 1.f / (1.f + expf(-s));
    }
    __syncthreads();
    if (l == 0) {
        // top-3 on gate+bias, strict > keeps lowest index on ties (jax top_k)
        unsigned chosen = 0;
        int be[3]; float bw[3];
        float gsum = 0.f;
        for (int e = 0; e < NE; e++) gsum += gv[w][e];
        #pragma unroll
        for (int k = 0; k < 3; k++) {
            float m = -1e30f; int mi = 0;
            for (int e = 0; e < NE; e++) {
                float kv = gv[w][e] + bias[e];
                if (!((chosen >> e) & 1u) && kv > m) { m = kv; mi = e; }
            }
            chosen |= 1u << mi;
            be[k] = mi; bw[k] = gv[w][mi];
        }
        float inv = 1.f / (bw[0] + bw[1] + bw[2]);
        #pragma unroll
        for (int k = 0; k < 3; k++) {
            tokE[t * 3 + k] = be[k];
            tokW[t * 3 + k] = bw[k] * inv;
            atomicAdd(&counts[be[k]], 1);
        }
        float ginv = 1.f / gsum;
        for (int e = 0; e < NE; e++) atomicAdd(&Psum[e], gv[w][e] * ginv);
    }
}

__global__ void k_scan(const int* __restrict__ counts, const float* __restrict__ Psum,
                       int* __restrict__ offs, int* __restrict__ toffs,
                       int* __restrict__ total, float* __restrict__ outAux)
{
    if (threadIdx.x != 0 || blockIdx.x != 0) return;
    int off = 0, toff = 0;
    for (int e = 0; e < NG; e++) {
        int c = (e < NE) ? counts[e] : TT;
        offs[e] = off; toffs[e] = toff;
        off += c; toff += (c + BM - 1) / BM;
    }
    offs[NG] = off; toffs[NG] = toff;
    *total = toff;
    float aux = 0.f;
    for (int e = 0; e < NE; e++) {
        float P = Psum[e] / (float)TT;
        float F = (float)NE * (float)counts[e] / (float)(3 * TT);
        aux += P * F;
    }
    outAux[0] = aux;
    for (int e = 0; e < NE; e++) outAux[1 + e] = (float)counts[e];
}

__global__ void k_scatter(const int* __restrict__ tokE, const float* __restrict__ tokW,
                          const int* __restrict__ offs, int* __restrict__ curs,
                          int* __restrict__ ltok, float* __restrict__ lw)
{
    int t = blockIdx.x * 256 + threadIdx.x;
    if (t >= TT) return;
    #pragma unroll
    for (int k = 0; k < 3; k++) {
        int e = tokE[t * 3 + k];
        int pos = atomicAdd(&curs[e], 1);
        int idx = offs[e] + pos;
        ltok[idx] = t; lw[idx] = tokW[t * 3 + k];
    }
    ltok[3 * TT + t] = t;   // shared-expert assignment, weight 1
    lw[3 * TT + t] = 1.f;
}

// grouped GEMM1 + exact GeLU: H[a, :] = gelu(x[tok(a), :] @ W1[e] + b1[e])
__global__ __launch_bounds__(256) void k_ffn1(
    const float* __restrict__ x, const float* __restrict__ W1,
    const float* __restrict__ b1, const float* __restrict__ sW1,
    const float* __restrict__ sb1, const int* __restrict__ toffs,
    const int* __restrict__ offs, const int* __restrict__ total,
    const int* __restrict__ ltok, float* __restrict__ H)
{
    const int tb = blockIdx.x;
    if (tb >= *total) return;
    int e = 0;
    while (toffs[e + 1] <= tb) e++;
    const int a0 = offs[e] + (tb - toffs[e]) * BM;
    const int acount = min(offs[e + 1] - a0, BM);
    const float* W = (e < NE) ? (W1 + (size_t)e * DD * HH) : sW1;
    const float* bb = (e < NE) ? (b1 + e * HH) : sb1;
    const int nb = blockIdx.y * BN;

    __shared__ float Xs[BM][36];    // pad to 36 -> float4-aligned, conflict-free
    __shared__ float Ws[BK][BN];
    __shared__ int rows[BM];
    const int tid = threadIdx.x;
    if (tid < BM) rows[tid] = (tid < acount) ? ltok[a0 + tid] : -1;
    __syncthreads();

    const int tx = tid & 15, ty = tid >> 4;
    const int m0 = ty * 4, n0 = tx * 8;
    float acc[4][8] = {};

    for (int kb = 0; kb < DD; kb += BK) {
        {   // stage X tile 64x32
            int col = tid & 31, r0 = tid >> 5;
            #pragma unroll
            for (int r = 0; r < BM; r += 8) {
                int row = r + r0;
                int tok = rows[row];
                Xs[row][col] = (tok >= 0) ? x[(size_t)tok * DD + kb + col] : 0.f;
            }
        }
        {   // stage W tile 32x128 via float4
            int u = tid;
            #pragma unroll
            for (int r = 0; r < 4; r++, u += 256) {
                int k = u >> 5, c4 = (u & 31) << 2;
                *(float4*)&Ws[k][c4] = *(const float4*)(W + (size_t)(kb + k) * HH + nb + c4);
            }
        }
        __syncthreads();
        #pragma unroll
        for (int k4 = 0; k4 < BK; k4 += 4) {
            float4 av[4];
            #pragma unroll
            for (int i = 0; i < 4; i++) av[i] = *(const float4*)&Xs[m0 + i][k4];
            #pragma unroll
            for (int kk = 0; kk < 4; kk++) {
                float4 b0 = *(const float4*)&Ws[k4 + kk][n0];
                float4 b1v = *(const float4*)&Ws[k4 + kk][n0 + 4];
                float bj[8] = {b0.x, b0.y, b0.z, b0.w, b1v.x, b1v.y, b1v.z, b1v.w};
                #pragma unroll
                for (int i = 0; i < 4; i++) {
                    float a = (kk == 0) ? av[i].x : (kk == 1) ? av[i].y
                             : (kk == 2) ? av[i].z : av[i].w;
                    #pragma unroll
                    for (int j = 0; j < 8; j++) acc[i][j] = fmaf(a, bj[j], acc[i][j]);
                }
            }
        }
        __syncthreads();
    }
    #pragma unroll
    for (int i = 0; i < 4; i++) {
        int row = m0 + i;
        if (row < acount) {
            float* dst = H + (size_t)(a0 + row) * HH + nb + n0;
            float o[8];
            #pragma unroll
            for (int j = 0; j < 8; j++) {
                float v = acc[i][j] + bb[nb + n0 + j];
                o[j] = 0.5f * v * (1.f + erff(v * 0.70710678118f));  // exact gelu
            }
            *(float4*)dst = make_float4(o[0], o[1], o[2], o[3]);
            *(float4*)(dst + 4) = make_float4(o[4], o[5], o[6], o[7]);
        }
    }
}

// grouped GEMM2 + weighted combine: out[tok(a), :] += w(a) * (H[a, :] @ W2[e] + b2[e])
__global__ __launch_bounds__(256) void k_ffn2(
    const float* __restrict__ H, const float* __restrict__ W2,
    const float* __restrict__ b2, const float* __restrict__ sW2,
    const float* __restrict__ sb2, const int* __restrict__ toffs,
    const int* __restrict__ offs, const int* __restrict__ total,
    const int* __restrict__ ltok, const float* __restrict__ lw,
    float* __restrict__ out)
{
    const int tb = blockIdx.x;
    if (tb >= *total) return;
    int e = 0;
    while (toffs[e + 1] <= tb) e++;
    const int a0 = offs[e] + (tb - toffs[e]) * BM;
    const int acount = min(offs[e + 1] - a0, BM);
    const float* W = (e < NE) ? (W2 + (size_t)e * HH * DD) : sW2;
    const float* bb = (e < NE) ? (b2 + e * DD) : sb2;
    const int nb = blockIdx.y * BN;

    __shared__ float As[BM][36];
    __shared__ float Ws[BK][BN];
    __shared__ int rows[BM];
    __shared__ float wts[BM];
    const int tid = threadIdx.x;
    if (tid < BM) {
        rows[tid] = (tid < acount) ? ltok[a0 + tid] : -1;
        wts[tid] = (tid < acount) ? lw[a0 + tid] : 0.f;
    }
    __syncthreads();

    const int tx = tid & 15, ty = tid >> 4;
    const int m0 = ty * 4, n0 = tx * 8;
    float acc[4][8] = {};

    for (int kb = 0; kb < HH; kb += BK) {
        {
            int col = tid & 31, r0 = tid >> 5;
            #pragma unroll
            for (int r = 0; r < BM; r += 8) {
                int row = r + r0;
                As[row][col] = (row < acount) ? H[(size_t)(a0 + row) * HH + kb + col] : 0.f;
            }
        }
        {
            int u = tid;
            #pragma unroll
            for (int r = 0; r < 4; r++, u += 256) {
                int k = u >> 5, c4 = (u & 31) << 2;
                *(float4*)&Ws[k][c4] = *(const float4*)(W + (size_t)(kb + k) * DD + nb + c4);
            }
        }
        __syncthreads();
        #pragma unroll
        for (int k4 = 0; k4 < BK; k4 += 4) {
            float4 av[4];
            #pragma unroll
            for (int i = 0; i < 4; i++) av[i] = *(const float4*)&As[m0 + i][k4];
            #pragma unroll
            for (int kk = 0; kk < 4; kk++) {
                float4 b0 = *(const float4*)&Ws[k4 + kk][n0];
                float4 b1v = *(const float4*)&Ws[k4 + kk][n0 + 4];
                float bj[8] = {b0.x, b0.y, b0.z, b0.w, b1v.x, b1v.y, b1v.z, b1v.w};
                #pragma unroll
                for (int i = 0; i < 4; i++) {
                    float a = (kk == 0) ? av[i].x : (kk == 1) ? av[i].y
                             : (kk == 2) ? av[i].z : av[i].w;
                    #pragma unroll
                    for (int j = 0; j < 8; j++) acc[i][j] = fmaf(a, bj[j], acc[i][j]);
                }
            }
        }
        __syncthreads();
    }
    #pragma unroll
    for (int i = 0; i < 4; i++) {
        int row = m0 + i;
        if (row < acount) {
            int tok = rows[row];
            float wgt = wts[row];
            float* dst = out + (size_t)tok * DD + nb + n0;
            #pragma unroll
            for (int j = 0; j < 8; j++)
                atomicAdd(&dst[j], wgt * (acc[i][j] + bb[nb + n0 + j]));
        }
    }
}

extern "C" void kernel_launch(void* const* d_in, const int* in_sizes, int n_in,
                              void* d_out, int out_size, void* d_ws, size_t ws_size,
                              hipStream_t stream)
{
    const float* x    = (const float*)d_in[0];
    const float* gW   = (const float*)d_in[1];
    const float* gb   = (const float*)d_in[2];
    const float* bias = (const float*)d_in[3];
    const float* W1   = (const float*)d_in[4];
    const float* b1   = (const float*)d_in[5];
    const float* W2   = (const float*)d_in[6];
    const float* b2   = (const float*)d_in[7];
    const float* sW1  = (const float*)d_in[8];
    const float* sb1  = (const float*)d_in[9];
    const float* sW2  = (const float*)d_in[10];
    const float* sb2  = (const float*)d_in[11];
    float* out = (float*)d_out;
    float* wsf = (float*)d_ws;
    int*   wsi = (int*)d_ws;

    // zero output (we accumulate with atomics) and ws bookkeeping
    hipMemsetAsync(d_out, 0, (size_t)out_size * sizeof(float), stream);
    hipMemsetAsync(d_ws, 0, 1024, stream);

    int*   counts = wsi + WS_COUNTS;
    float* Psum   = wsf + WS_PSUM;
    int*   offs   = wsi + WS_OFFS;
    int*   toffs  = wsi + WS_TOFFS;
    int*   curs   = wsi + WS_CURS;
    int*   total  = wsi + WS_TOTAL;
    int*   tokE   = wsi + WS_TOKE;
    float* tokW   = wsf + WS_TOKW;
    int*   ltok   = wsi + WS_LTOK;
    float* lwt    = wsf + WS_LW;
    float* Hbuf   = wsf + WS_H;

    k_gate<<<TT / 4, 256, 0, stream>>>(x, gW, gb, bias, counts, Psum, tokE, tokW);
    k_scan<<<1, 64, 0, stream>>>(counts, Psum, offs, toffs, total, out + (size_t)TT * DD);
    k_scatter<<<TT / 256, 256, 0, stream>>>(tokE, tokW, offs, curs, ltok, lwt);
    k_ffn1<<<dim3(MAXTILES, HH / BN), 256, 0, stream>>>(x, W1, b1, sW1, sb1,
                                                        toffs, offs, total, ltok, Hbuf);
    k_ffn2<<<dim3(MAXTILES, DD / BN), 256, 0, stream>>>(Hbuf, W2, b2, sW2, sb2,
                                                        toffs, offs, total, ltok, lwt, out);
}

// Round 2
// 406.493 us; speedup vs baseline: 5.2278x; 5.2278x over previous
//
#include <hip/hip_runtime.h>
#include <math.h>

#define TT 4096
#define DD 1024
#define HH 768
#define NE 23
#define NG 24          // 23 experts + shared as group 23
#define BM 128
#define BN 128
#define BK 32
#define MAXT 160       // sum ceil(n_e/128) <= 118, + 32 shared tiles = 150

// ws layout in 4-byte words
#define WS_CURS   0        // 23*16 ints (1 cache line per expert)
#define WS_COUNTS 512
#define WS_PSUM   544
#define WS_OFFS   576      // 25
#define WS_TOFFS  608      // 25
#define WS_TOTAL  640
#define WS_TOKE   1024     // 12288
#define WS_TOKW   13312    // 12288
#define WS_LTOK   25600    // 16384
#define WS_LW     41984    // 16384
#define WS_PPART  58368    // 23*1024 floats
#define WS_CPART  81920    // 23*1024 ints
#define WS_HB_BYTES 524288 // H buffer: 16384*768 bf16 = 25.2 MB

typedef short bf16x8 __attribute__((ext_vector_type(8)));
typedef float f32x4 __attribute__((ext_vector_type(4)));

__device__ inline unsigned short bfr(float f) {   // f32 -> bf16 RNE
    unsigned u = __float_as_uint(f);
    u += 0x7fffu + ((u >> 16) & 1u);
    return (unsigned short)(u >> 16);
}

__global__ __launch_bounds__(256) void k_gate(
    const float* __restrict__ x, const float* __restrict__ gW,
    const float* __restrict__ gb, const float* __restrict__ bias,
    int* __restrict__ tokE, float* __restrict__ tokW,
    float* __restrict__ Ppart, int* __restrict__ Cpart)
{
    __shared__ float xs[4][DD];
    __shared__ float gv[4][NE];
    __shared__ float ginvs[4];
    __shared__ int sel[4][3];
    const int tid = threadIdx.x;
    const int t0 = blockIdx.x * 4;
    {   // stage 4 tokens of x
        const float4* src = (const float4*)(x + (size_t)t0 * DD);
        float4* dst = (float4*)&xs[0][0];
        #pragma unroll
        for (int i = 0; i < 4; i++) dst[tid + 256 * i] = src[tid + 256 * i];
    }
    __syncthreads();
    const int w = tid >> 6, l = tid & 63;
    const int t = t0 + w;
    if (l < NE) {
        float s0 = 0.f, s1 = 0.f, s2 = 0.f, s3 = 0.f;
        const float* xw = xs[w];
        for (int d = 0; d < DD; d += 4) {
            s0 = fmaf(xw[d + 0], gW[(d + 0) * NE + l], s0);
            s1 = fmaf(xw[d + 1], gW[(d + 1) * NE + l], s1);
            s2 = fmaf(xw[d + 2], gW[(d + 2) * NE + l], s2);
            s3 = fmaf(xw[d + 3], gW[(d + 3) * NE + l], s3);
        }
        float s = (s0 + s1) + (s2 + s3) + gb[l];
        gv[w][l] = 1.f / (1.f + expf(-s));
    }
    __syncthreads();
    if (l == 0) {
        unsigned chosen = 0;
        int be[3]; float bw[3];
        float gsum = 0.f;
        for (int e = 0; e < NE; e++) gsum += gv[w][e];
        #pragma unroll
        for (int k = 0; k < 3; k++) {
            float m = -1e30f; int mi = 0;
            for (int e = 0; e < NE; e++) {
                float kv = gv[w][e] + bias[e];
                if (!((chosen >> e) & 1u) && kv > m) { m = kv; mi = e; }
            }
            chosen |= 1u << mi;
            be[k] = mi; bw[k] = gv[w][mi];
        }
        float inv = 1.f / (bw[0] + bw[1] + bw[2]);
        #pragma unroll
        for (int k = 0; k < 3; k++) {
            tokE[t * 3 + k] = be[k];
            tokW[t * 3 + k] = bw[k] * inv;
            sel[w][k] = be[k];
        }
        ginvs[w] = 1.f / gsum;
    }
    __syncthreads();
    if (tid < NE) {   // per-block partials: NO global atomics
        float p = gv[0][tid] * ginvs[0] + gv[1][tid] * ginvs[1]
                + gv[2][tid] * ginvs[2] + gv[3][tid] * ginvs[3];
        Ppart[tid * 1024 + blockIdx.x] = p;
        int c = 0;
        #pragma unroll
        for (int w2 = 0; w2 < 4; w2++)
            #pragma unroll
            for (int k = 0; k < 3; k++) c += (sel[w2][k] == tid);
        Cpart[tid * 1024 + blockIdx.x] = c;
    }
}

__global__ __launch_bounds__(256) void k_reduce(
    const float* __restrict__ Ppart, const int* __restrict__ Cpart,
    int* __restrict__ counts, float* __restrict__ Psum)
{
    const int e = blockIdx.x;
    const int tid = threadIdx.x;
    float s = 0.f; int c = 0;
    for (int i = tid; i < 1024; i += 256) {
        s += Ppart[e * 1024 + i];
        c += Cpart[e * 1024 + i];
    }
    #pragma unroll
    for (int off = 32; off >= 1; off >>= 1) {
        s += __shfl_down(s, off, 64);
        c += __shfl_down(c, off, 64);
    }
    __shared__ float ss[4]; __shared__ int sc[4];
    if ((tid & 63) == 0) { ss[tid >> 6] = s; sc[tid >> 6] = c; }
    __syncthreads();
    if (tid == 0) {
        Psum[e] = ss[0] + ss[1] + ss[2] + ss[3];
        counts[e] = sc[0] + sc[1] + sc[2] + sc[3];
    }
}

__global__ void k_scan(const int* __restrict__ counts, const float* __restrict__ Psum,
                       int* __restrict__ offs, int* __restrict__ toffs,
                       int* __restrict__ total, float* __restrict__ outAux)
{
    if (threadIdx.x != 0 || blockIdx.x != 0) return;
    int off = 0, toff = 0;
    for (int e = 0; e < NG; e++) {
        int c = (e < NE) ? counts[e] : TT;
        offs[e] = off; toffs[e] = toff;
        off += c; toff += (c + BM - 1) / BM;
    }
    offs[NG] = off; toffs[NG] = toff;
    *total = toff;
    float aux = 0.f;
    for (int e = 0; e < NE; e++) {
        float P = Psum[e] / (float)TT;
        float F = (float)NE * (float)counts[e] / (float)(3 * TT);
        aux += P * F;
    }
    outAux[0] = aux;
    for (int e = 0; e < NE; e++) outAux[1 + e] = (float)counts[e];
}

__global__ void k_scatter(const int* __restrict__ tokE, const float* __restrict__ tokW,
                          const int* __restrict__ offs, int* __restrict__ curs,
                          int* __restrict__ ltok, float* __restrict__ lw)
{
    int t = blockIdx.x * 256 + threadIdx.x;
    if (t >= TT) return;
    #pragma unroll
    for (int k = 0; k < 3; k++) {
        int e = tokE[t * 3 + k];
        int pos = atomicAdd(&curs[e * 16], 1);   // 1 cache line per expert counter
        int idx = offs[e] + pos;
        ltok[idx] = t; lw[idx] = tokW[t * 3 + k];
    }
    ltok[3 * TT + t] = t;
    lw[3 * TT + t] = 1.f;
}

// grouped bf16-MFMA GEMM1 + exact GeLU: H[a,:] = gelu(x[tok(a),:] @ W1[e] + b1[e]) (bf16 out)
__global__ __launch_bounds__(256) void k_mm1(
    const float* __restrict__ x, const float* __restrict__ W1,
    const float* __restrict__ b1, const float* __restrict__ sW1,
    const float* __restrict__ sb1, const int* __restrict__ toffs,
    const int* __restrict__ offs, const int* __restrict__ total,
    const int* __restrict__ ltok, unsigned short* __restrict__ H)
{
    const int tb = blockIdx.x;
    if (tb >= *total) return;
    int e = 0;
    while (toffs[e + 1] <= tb) e++;
    const int a0 = offs[e] + (tb - toffs[e]) * BM;
    const int acount = min(offs[e + 1] - a0, BM);
    const float* W = (e < NE) ? (W1 + (size_t)e * DD * HH) : sW1;
    const float* bb = (e < NE) ? (b1 + e * HH) : sb1;
    const int nb = blockIdx.y * BN;

    __shared__ unsigned short Asl[BM * 40];   // [row][k], stride 40 (80B: 16B-aligned b128, ~2-way)
    __shared__ unsigned short Bsl[BN * 40];   // [n][k]  transposed
    __shared__ int rows[BM];
    const int tid = threadIdx.x;
    if (tid < BM) rows[tid] = (tid < acount) ? ltok[a0 + tid] : -1;
    __syncthreads();

    const int wid = tid >> 6, lane = tid & 63;
    const int wr = wid >> 1, wc = wid & 1;
    const int l15 = lane & 15, l4 = lane >> 4;
    f32x4 acc[4][4];
    #pragma unroll
    for (int m = 0; m < 4; m++)
        #pragma unroll
        for (int n = 0; n < 4; n++) acc[m][n] = (f32x4){0.f, 0.f, 0.f, 0.f};

    for (int kb = 0; kb < DD; kb += BK) {
        #pragma unroll
        for (int it = 0; it < 4; it++) {   // stage A (gather rows, f32->bf16)
            int row = (tid >> 3) + 32 * it;
            int kc = (tid & 7) * 4;
            int tok = rows[row];
            float4 v = (tok >= 0) ? *(const float4*)(x + (size_t)tok * DD + kb + kc)
                                  : make_float4(0.f, 0.f, 0.f, 0.f);
            ushort4 h = make_ushort4(bfr(v.x), bfr(v.y), bfr(v.z), bfr(v.w));
            *(ushort4*)&Asl[row * 40 + kc] = h;
        }
        #pragma unroll
        for (int it = 0; it < 16; it++) {  // stage B transposed (f32->bf16)
            int g = tid + 256 * it;
            int k = g >> 7, n = g & 127;
            Bsl[n * 40 + k] = bfr(W[(size_t)(kb + k) * HH + nb + n]);
        }
        __syncthreads();
        bf16x8 af[4], bf[4];
        #pragma unroll
        for (int f = 0; f < 4; f++) {
            af[f] = *(const bf16x8*)&Asl[(wr * 64 + f * 16 + l15) * 40 + l4 * 8];
            bf[f] = *(const bf16x8*)&Bsl[(wc * 64 + f * 16 + l15) * 40 + l4 * 8];
        }
        #pragma unroll
        for (int m = 0; m < 4; m++)
            #pragma unroll
            for (int n = 0; n < 4; n++)
                acc[m][n] = __builtin_amdgcn_mfma_f32_16x16x32_bf16(af[m], bf[n], acc[m][n], 0, 0, 0);
        __syncthreads();
    }
    #pragma unroll
    for (int m = 0; m < 4; m++) {
        int rbase = wr * 64 + m * 16 + l4 * 4;
        #pragma unroll
        for (int n = 0; n < 4; n++) {
            int col = nb + wc * 64 + n * 16 + l15;
            float bv = bb[col];
            #pragma unroll
            for (int i = 0; i < 4; i++) {
                int r = rbase + i;
                if (r < acount) {
                    float v = acc[m][n][i] + bv;
                    float g = 0.5f * v * (1.f + erff(v * 0.70710678118f));
                    H[(size_t)(a0 + r) * HH + col] = bfr(g);
                }
            }
        }
    }
}

// grouped bf16-MFMA GEMM2 + weighted combine: out[tok(a),:] += w(a)*(H[a,:] @ W2[e] + b2[e])
__global__ __launch_bounds__(256) void k_mm2(
    const unsigned short* __restrict__ H, const float* __restrict__ W2,
    const float* __restrict__ b2, const float* __restrict__ sW2,
    const float* __restrict__ sb2, const int* __restrict__ toffs,
    const int* __restrict__ offs, const int* __restrict__ total,
    const int* __restrict__ ltok, const float* __restrict__ lw,
    float* __restrict__ out)
{
    const int tb = blockIdx.x;
    if (tb >= *total) return;
    int e = 0;
    while (toffs[e + 1] <= tb) e++;
    const int a0 = offs[e] + (tb - toffs[e]) * BM;
    const int acount = min(offs[e + 1] - a0, BM);
    const float* W = (e < NE) ? (W2 + (size_t)e * HH * DD) : sW2;
    const float* bb = (e < NE) ? (b2 + e * DD) : sb2;
    const int nb = blockIdx.y * BN;

    __shared__ unsigned short Asl[BM * 40];
    __shared__ unsigned short Bsl[BN * 40];
    __shared__ int rows[BM];
    __shared__ float wts[BM];
    const int tid = threadIdx.x;
    if (tid < BM) {
        rows[tid] = (tid < acount) ? ltok[a0 + tid] : -1;
        wts[tid]  = (tid < acount) ? lw[a0 + tid] : 0.f;
    }
    __syncthreads();

    const int wid = tid >> 6, lane = tid & 63;
    const int wr = wid >> 1, wc = wid & 1;
    const int l15 = lane & 15, l4 = lane >> 4;
    f32x4 acc[4][4];
    #pragma unroll
    for (int m = 0; m < 4; m++)
        #pragma unroll
        for (int n = 0; n < 4; n++) acc[m][n] = (f32x4){0.f, 0.f, 0.f, 0.f};

    for (int kb = 0; kb < HH; kb += BK) {
        #pragma unroll
        for (int it = 0; it < 2; it++) {   // stage A: H already bf16, 16B copies
            int f = tid + 256 * it;
            int row = f >> 2, k8 = (f & 3) * 8;
            uint4 v = make_uint4(0u, 0u, 0u, 0u);
            if (row < acount)
                v = *(const uint4*)(H + (size_t)(a0 + row) * HH + kb + k8);
            *(uint4*)&Asl[row * 40 + k8] = v;
        }
        #pragma unroll
        for (int it = 0; it < 16; it++) {  // stage B transposed
            int g = tid + 256 * it;
            int k = g >> 7, n = g & 127;
            Bsl[n * 40 + k] = bfr(W[(size_t)(kb + k) * DD + nb + n]);
        }
        __syncthreads();
        bf16x8 af[4], bf[4];
        #pragma unroll
        for (int f = 0; f < 4; f++) {
            af[f] = *(const bf16x8*)&Asl[(wr * 64 + f * 16 + l15) * 40 + l4 * 8];
            bf[f] = *(const bf16x8*)&Bsl[(wc * 64 + f * 16 + l15) * 40 + l4 * 8];
        }
        #pragma unroll
        for (int m = 0; m < 4; m++)
            #pragma unroll
            for (int n = 0; n < 4; n++)
                acc[m][n] = __builtin_amdgcn_mfma_f32_16x16x32_bf16(af[m], bf[n], acc[m][n], 0, 0, 0);
        __syncthreads();
    }
    #pragma unroll
    for (int m = 0; m < 4; m++) {
        int rbase = wr * 64 + m * 16 + l4 * 4;
        #pragma unroll
        for (int n = 0; n < 4; n++) {
            int col = nb + wc * 64 + n * 16 + l15;
            float bv = bb[col];
            #pragma unroll
            for (int i = 0; i < 4; i++) {
                int r = rbase + i;
                if (r < acount) {
                    int tok = rows[r];
                    atomicAdd(out + (size_t)tok * DD + col, wts[r] * (acc[m][n][i] + bv));
                }
            }
        }
    }
}

extern "C" void kernel_launch(void* const* d_in, const int* in_sizes, int n_in,
                              void* d_out, int out_size, void* d_ws, size_t ws_size,
                              hipStream_t stream)
{
    const float* x    = (const float*)d_in[0];
    const float* gW   = (const float*)d_in[1];
    const float* gb   = (const float*)d_in[2];
    const float* bias = (const float*)d_in[3];
    const float* W1   = (const float*)d_in[4];
    const float* b1   = (const float*)d_in[5];
    const float* W2   = (const float*)d_in[6];
    const float* b2   = (const float*)d_in[7];
    const float* sW1  = (const float*)d_in[8];
    const float* sb1  = (const float*)d_in[9];
    const float* sW2  = (const float*)d_in[10];
    const float* sb2  = (const float*)d_in[11];
    float* out = (float*)d_out;
    float* wsf = (float*)d_ws;
    int*   wsi = (int*)d_ws;

    hipMemsetAsync(d_out, 0, (size_t)out_size * sizeof(float), stream);
    hipMemsetAsync(d_ws, 0, 2048, stream);   // curs only

    int*   curs   = wsi + WS_CURS;
    int*   counts = wsi + WS_COUNTS;
    float* Psum   = wsf + WS_PSUM;
    int*   offs   = wsi + WS_OFFS;
    int*   toffs  = wsi + WS_TOFFS;
    int*   total  = wsi + WS_TOTAL;
    int*   tokE   = wsi + WS_TOKE;
    float* tokW   = wsf + WS_TOKW;
    int*   ltok   = wsi + WS_LTOK;
    float* lwt    = wsf + WS_LW;
    float* Ppart  = wsf + WS_PPART;
    int*   Cpart  = wsi + WS_CPART;
    unsigned short* Hb = (unsigned short*)((char*)d_ws + WS_HB_BYTES);

    k_gate<<<TT / 4, 256, 0, stream>>>(x, gW, gb, bias, tokE, tokW, Ppart, Cpart);
    k_reduce<<<NE, 256, 0, stream>>>(Ppart, Cpart, counts, Psum);
    k_scan<<<1, 64, 0, stream>>>(counts, Psum, offs, toffs, total, out + (size_t)TT * DD);
    k_scatter<<<TT / 256, 256, 0, stream>>>(tokE, tokW, offs, curs, ltok, lwt);
    k_mm1<<<dim3(MAXT, HH / BN), 256, 0, stream>>>(x, W1, b1, sW1, sb1,
                                                   toffs, offs, total, ltok, Hb);
    k_mm2<<<dim3(MAXT, DD / BN), 256, 0, stream>>>(Hb, W2, b2, sW2, sb2,
                                                   toffs, offs, total, ltok, lwt, out);
}

// Round 3
// 294.263 us; speedup vs baseline: 7.2216x; 1.3814x over previous
//
#include <hip/hip_runtime.h>
#include <math.h>

#define TT 4096
#define DD 1024
#define HH 768
#define NE 23
#define NG 24          // 23 experts + shared as group 23
#define BM 128
#define BN 128
#define BK 64
#define MAXT 160       // sum ceil(n_e/128) <= 118, + 32 shared tiles = 150
#define KB1 16         // DD/64
#define KB2 12         // HH/64
#define NY1 6          // HH/BN
#define NY2 8          // DD/BN
#define NWG1 (MAXT*NY1)   // 960  (div by 8)
#define NWG2 (MAXT*NY2)   // 1280 (div by 8)

// ws word offsets (misc, < 512KB)
#define WS_CURS   0        // 23*16 ints (1 cache line per expert)
#define WS_COUNTS 512
#define WS_PSUM   544
#define WS_OFFS   576
#define WS_TOFFS  608
#define WS_TOTAL  640
#define WS_TOKE   1024
#define WS_TOKW   13312
#define WS_LTOK   25600
#define WS_LW     41984
#define WS_PPART  58368    // 23*1024 floats
#define WS_CPART  81920    // 23*1024 ints
// ws byte offsets (big buffers)
#define XB_OFF  ((size_t)524288)      // xb bf16: 4096*1024*2  = 8388608
#define H_OFF   ((size_t)8912896)     // H  bf16: 16384*768*2  = 25165824
#define W1B_OFF ((size_t)34078720)    // W1 blocked bf16: 24*16*768*64*2 = 37748736
#define W2B_OFF ((size_t)71827456)    // W2 blocked bf16: 24*12*1024*64*2 = 37748736
                                      // total ws use ~104.5 MB

typedef short bf16x8 __attribute__((ext_vector_type(8)));
typedef float f32x4 __attribute__((ext_vector_type(4)));
typedef unsigned short u16x8 __attribute__((ext_vector_type(8)));

__device__ inline unsigned short bfr(float f) {   // f32 -> bf16 RNE
    unsigned u = __float_as_uint(f);
    u += 0x7fffu + ((u >> 16) & 1u);
    return (unsigned short)(u >> 16);
}

__device__ __forceinline__ void gl_lds16(const void* g, void* l) {
    __builtin_amdgcn_global_load_lds(
        (const __attribute__((address_space(1))) unsigned int*)g,
        (__attribute__((address_space(3))) unsigned int*)l, 16, 0, 0);
}

__global__ __launch_bounds__(256) void k_gate(
    const float* __restrict__ x, const float* __restrict__ gW,
    const float* __restrict__ gb, const float* __restrict__ bias,
    int* __restrict__ tokE, float* __restrict__ tokW,
    float* __restrict__ Ppart, int* __restrict__ Cpart)
{
    __shared__ float xs[4][DD];
    __shared__ float gv[4][NE];
    __shared__ float ginvs[4];
    __shared__ int sel[4][3];
    const int tid = threadIdx.x;
    const int t0 = blockIdx.x * 4;
    {
        const float4* src = (const float4*)(x + (size_t)t0 * DD);
        float4* dst = (float4*)&xs[0][0];
        #pragma unroll
        for (int i = 0; i < 4; i++) dst[tid + 256 * i] = src[tid + 256 * i];
    }
    __syncthreads();
    const int w = tid >> 6, l = tid & 63;
    const int t = t0 + w;
    if (l < NE) {
        float s0 = 0.f, s1 = 0.f, s2 = 0.f, s3 = 0.f;
        const float* xw = xs[w];
        for (int d = 0; d < DD; d += 4) {
            s0 = fmaf(xw[d + 0], gW[(d + 0) * NE + l], s0);
            s1 = fmaf(xw[d + 1], gW[(d + 1) * NE + l], s1);
            s2 = fmaf(xw[d + 2], gW[(d + 2) * NE + l], s2);
            s3 = fmaf(xw[d + 3], gW[(d + 3) * NE + l], s3);
        }
        float s = (s0 + s1) + (s2 + s3) + gb[l];
        gv[w][l] = 1.f / (1.f + expf(-s));
    }
    __syncthreads();
    if (l == 0) {
        unsigned chosen = 0;
        int be[3]; float bw[3];
        float gsum = 0.f;
        for (int e = 0; e < NE; e++) gsum += gv[w][e];
        #pragma unroll
        for (int k = 0; k < 3; k++) {
            float m = -1e30f; int mi = 0;
            for (int e = 0; e < NE; e++) {
                float kv = gv[w][e] + bias[e];
                if (!((chosen >> e) & 1u) && kv > m) { m = kv; mi = e; }
            }
            chosen |= 1u << mi;
            be[k] = mi; bw[k] = gv[w][mi];
        }
        float inv = 1.f / (bw[0] + bw[1] + bw[2]);
        #pragma unroll
        for (int k = 0; k < 3; k++) {
            tokE[t * 3 + k] = be[k];
            tokW[t * 3 + k] = bw[k] * inv;
            sel[w][k] = be[k];
        }
        ginvs[w] = 1.f / gsum;
    }
    __syncthreads();
    if (tid < NE) {   // per-block partials: NO global atomics
        float p = gv[0][tid] * ginvs[0] + gv[1][tid] * ginvs[1]
                + gv[2][tid] * ginvs[2] + gv[3][tid] * ginvs[3];
        Ppart[tid * 1024 + blockIdx.x] = p;
        int c = 0;
        #pragma unroll
        for (int w2 = 0; w2 < 4; w2++)
            #pragma unroll
            for (int k = 0; k < 3; k++) c += (sel[w2][k] == tid);
        Cpart[tid * 1024 + blockIdx.x] = c;
    }
}

__global__ __launch_bounds__(256) void k_reduce(
    const float* __restrict__ Ppart, const int* __restrict__ Cpart,
    int* __restrict__ counts, float* __restrict__ Psum)
{
    const int e = blockIdx.x;
    const int tid = threadIdx.x;
    float s = 0.f; int c = 0;
    for (int i = tid; i < 1024; i += 256) {
        s += Ppart[e * 1024 + i];
        c += Cpart[e * 1024 + i];
    }
    #pragma unroll
    for (int off = 32; off >= 1; off >>= 1) {
        s += __shfl_down(s, off, 64);
        c += __shfl_down(c, off, 64);
    }
    __shared__ float ss[4]; __shared__ int sc[4];
    if ((tid & 63) == 0) { ss[tid >> 6] = s; sc[tid >> 6] = c; }
    __syncthreads();
    if (tid == 0) {
        Psum[e] = ss[0] + ss[1] + ss[2] + ss[3];
        counts[e] = sc[0] + sc[1] + sc[2] + sc[3];
    }
}

__global__ void k_scan(const int* __restrict__ counts, const float* __restrict__ Psum,
                       int* __restrict__ offs, int* __restrict__ toffs,
                       int* __restrict__ total, float* __restrict__ outAux)
{
    if (threadIdx.x != 0 || blockIdx.x != 0) return;
    int off = 0, toff = 0;
    for (int e = 0; e < NG; e++) {
        int c = (e < NE) ? counts[e] : TT;
        offs[e] = off; toffs[e] = toff;
        off += c; toff += (c + BM - 1) / BM;
    }
    offs[NG] = off; toffs[NG] = toff;
    *total = toff;
    float aux = 0.f;
    for (int e = 0; e < NE; e++) {
        float P = Psum[e] / (float)TT;
        float F = (float)NE * (float)counts[e] / (float)(3 * TT);
        aux += P * F;
    }
    outAux[0] = aux;
    for (int e = 0; e < NE; e++) outAux[1 + e] = (float)counts[e];
}

__global__ void k_scatter(const int* __restrict__ tokE, const float* __restrict__ tokW,
                          const int* __restrict__ offs, int* __restrict__ curs,
                          int* __restrict__ ltok, float* __restrict__ lw)
{
    int t = blockIdx.x * 256 + threadIdx.x;
    if (t >= TT) return;
    #pragma unroll
    for (int k = 0; k < 3; k++) {
        int e = tokE[t * 3 + k];
        int pos = atomicAdd(&curs[e * 16], 1);
        int idx = offs[e] + pos;
        ltok[idx] = t; lw[idx] = tokW[t * 3 + k];
    }
    ltok[3 * TT + t] = t;
    lw[3 * TT + t] = 1.f;
}

// x f32 -> bf16
__global__ __launch_bounds__(256) void k_cvt_x(const float* __restrict__ x,
                                               unsigned short* __restrict__ xb)
{
    const int tid = threadIdx.x;
    #pragma unroll
    for (int it = 0; it < 4; it++) {
        int idx = blockIdx.x * 1024 + it * 256 + tid;
        float4 v = ((const float4*)x)[idx];
        ((ushort4*)xb)[idx] = make_ushort4(bfr(v.x), bfr(v.y), bfr(v.z), bfr(v.w));
    }
}

// W [K][N] f32 (per expert, + shared at slot NE) -> blocked transposed bf16:
// dst[((e*(K/64) + kb)*N + n)*64 + p*8 .. +8] holds k = kb*64 + j*8..+8 of col n,
// at PHYSICAL granule p = j ^ (n&7)  (XOR swizzle baked into global layout)
__global__ __launch_bounds__(256) void k_cvt_w(
    const float* __restrict__ W, const float* __restrict__ Ws,
    int K, int N, unsigned short* __restrict__ dst)
{
    const int e = blockIdx.z, kb = blockIdx.y;
    const int KBt = gridDim.y;
    const int w = threadIdx.x >> 6, lane = threadIdx.x & 63;
    const int n = blockIdx.x * 64 + lane;
    const float* src = (e < NE) ? (W + (size_t)e * K * N) : Ws;
    #pragma unroll
    for (int h = 0; h < 2; h++) {
        const int k0 = kb * 64 + h * 32 + w * 8;
        float v[8];
        #pragma unroll
        for (int j = 0; j < 8; j++) v[j] = src[(size_t)(k0 + j) * N + n];
        u16x8 u;
        #pragma unroll
        for (int j = 0; j < 8; j++) u[j] = bfr(v[j]);
        const int p = (h * 4 + w) ^ (lane & 7);
        *(u16x8*)(dst + ((size_t)(e * KBt + kb) * N + n) * 64 + p * 8) = u;
    }
}

// grouped bf16-MFMA GEMM1 + exact GeLU: H[a,:] = gelu(x[tok(a),:] @ W1[e] + b1[e])
__global__ __launch_bounds__(256) void k_mm1(
    const unsigned short* __restrict__ xb, const unsigned short* __restrict__ W1b,
    const float* __restrict__ b1, const float* __restrict__ sb1,
    const int* __restrict__ toffs, const int* __restrict__ offs,
    const int* __restrict__ total, const int* __restrict__ ltok,
    unsigned short* __restrict__ H)
{
    const int id = blockIdx.x;
    const int wg = (id & 7) * (NWG1 / 8) + (id >> 3);   // XCD-aware bijective swizzle
    const int ns = wg / MAXT;
    const int tb = wg % MAXT;
    if (tb >= *total) return;
    int e = 0;
    while (toffs[e + 1] <= tb) e++;
    const int a0 = offs[e] + (tb - toffs[e]) * BM;
    const int acount = min(offs[e + 1] - a0, BM);
    const float* bb = (e < NE) ? (b1 + e * HH) : sb1;
    const int nb = ns * BN;

    __shared__ unsigned short As[BM * BK];   // linear, swizzle in addressing
    __shared__ unsigned short Bs[BN * BK];
    __shared__ int rows[BM];
    const int tid = threadIdx.x;
    if (tid < BM) rows[tid] = ltok[a0 + min(tid, acount - 1)];  // clamped: safe gather
    __syncthreads();

    const int wid = tid >> 6, lane = tid & 63;
    const int wr = wid >> 1, wc = wid & 1;
    const int l15 = lane & 15, l4 = lane >> 4;
    f32x4 acc[4][4];
    #pragma unroll
    for (int m = 0; m < 4; m++)
        #pragma unroll
        for (int n = 0; n < 4; n++) acc[m][n] = (f32x4){0.f, 0.f, 0.f, 0.f};

    const unsigned short* wbase = W1b + ((size_t)e * KB1 * HH + nb) * 64;

    for (int kb = 0; kb < KB1; kb++) {
        #pragma unroll
        for (int c = 0; c < 4; c++) {       // A: gather rows of xb, pre-swizzled src
            int G = (wid * 4 + c) * 64 + lane;
            int row = G >> 3, j = G & 7;
            gl_lds16(xb + (size_t)rows[row] * DD + kb * 64 + ((j ^ (row & 7)) << 3),
                     &As[G * 8]);
        }
        const unsigned short* wb = wbase + (size_t)kb * (HH * 64);
        #pragma unroll
        for (int c = 0; c < 4; c++) {       // B: contiguous 16KB stream
            int G = (wid * 4 + c) * 64 + lane;
            gl_lds16(wb + G * 8, &Bs[G * 8]);
        }
        __syncthreads();
        #pragma unroll
        for (int kh = 0; kh < 2; kh++) {
            bf16x8 af[4], bf[4];
            #pragma unroll
            for (int f = 0; f < 4; f++) {
                int ar = wr * 64 + f * 16 + l15;
                int br = wc * 64 + f * 16 + l15;
                int pg = (kh << 2) + l4;
                af[f] = *(const bf16x8*)&As[ar * 64 + ((pg ^ (ar & 7)) << 3)];
                bf[f] = *(const bf16x8*)&Bs[br * 64 + ((pg ^ (br & 7)) << 3)];
            }
            #pragma unroll
            for (int m = 0; m < 4; m++)
                #pragma unroll
                for (int n = 0; n < 4; n++)
                    acc[m][n] = __builtin_amdgcn_mfma_f32_16x16x32_bf16(af[m], bf[n], acc[m][n], 0, 0, 0);
        }
        __syncthreads();
    }
    #pragma unroll
    for (int m = 0; m < 4; m++) {
        int rbase = wr * 64 + m * 16 + l4 * 4;
        #pragma unroll
        for (int n = 0; n < 4; n++) {
            int col = nb + wc * 64 + n * 16 + l15;
            float bv = bb[col];
            #pragma unroll
            for (int i = 0; i < 4; i++) {
                int r = rbase + i;
                if (r < acount) {
                    float v = acc[m][n][i] + bv;
                    float g = 0.5f * v * (1.f + erff(v * 0.70710678118f));
                    H[(size_t)(a0 + r) * HH + col] = bfr(g);
                }
            }
        }
    }
}

// grouped bf16-MFMA GEMM2 + weighted combine
__global__ __launch_bounds__(256) void k_mm2(
    const unsigned short* __restrict__ H, const unsigned short* __restrict__ W2b,
    const float* __restrict__ b2, const float* __restrict__ sb2,
    const int* __restrict__ toffs, const int* __restrict__ offs,
    const int* __restrict__ total, const int* __restrict__ ltok,
    const float* __restrict__ lw, float* __restrict__ out)
{
    const int id = blockIdx.x;
    const int wg = (id & 7) * (NWG2 / 8) + (id >> 3);
    const int ns = wg / MAXT;
    const int tb = wg % MAXT;
    if (tb >= *total) return;
    int e = 0;
    while (toffs[e + 1] <= tb) e++;
    const int a0 = offs[e] + (tb - toffs[e]) * BM;
    const int acount = min(offs[e + 1] - a0, BM);
    const float* bb = (e < NE) ? (b2 + e * DD) : sb2;
    const int nb = ns * BN;

    __shared__ unsigned short As[BM * BK];
    __shared__ unsigned short Bs[BN * BK];
    __shared__ int rows[BM];
    __shared__ float wts[BM];
    const int tid = threadIdx.x;
    if (tid < BM) {
        rows[tid] = (tid < acount) ? ltok[a0 + tid] : -1;
        wts[tid]  = (tid < acount) ? lw[a0 + tid] : 0.f;
    }
    __syncthreads();

    const int wid = tid >> 6, lane = tid & 63;
    const int wr = wid >> 1, wc = wid & 1;
    const int l15 = lane & 15, l4 = lane >> 4;
    f32x4 acc[4][4];
    #pragma unroll
    for (int m = 0; m < 4; m++)
        #pragma unroll
        for (int n = 0; n < 4; n++) acc[m][n] = (f32x4){0.f, 0.f, 0.f, 0.f};

    const unsigned short* wbase = W2b + ((size_t)e * KB2 * DD + nb) * 64;

    for (int kb = 0; kb < KB2; kb++) {
        #pragma unroll
        for (int c = 0; c < 4; c++) {       // A: H rows are contiguous (a0+row)
            int G = (wid * 4 + c) * 64 + lane;
            int row = G >> 3, j = G & 7;
            gl_lds16(H + (size_t)(a0 + row) * HH + kb * 64 + ((j ^ (row & 7)) << 3),
                     &As[G * 8]);
        }
        const unsigned short* wb = wbase + (size_t)kb * (DD * 64);
        #pragma unroll
        for (int c = 0; c < 4; c++) {
            int G = (wid * 4 + c) * 64 + lane;
            gl_lds16(wb + G * 8, &Bs[G * 8]);
        }
        __syncthreads();
        #pragma unroll
        for (int kh = 0; kh < 2; kh++) {
            bf16x8 af[4], bf[4];
            #pragma unroll
            for (int f = 0; f < 4; f++) {
                int ar = wr * 64 + f * 16 + l15;
                int br = wc * 64 + f * 16 + l15;
                int pg = (kh << 2) + l4;
                af[f] = *(const bf16x8*)&As[ar * 64 + ((pg ^ (ar & 7)) << 3)];
                bf[f] = *(const bf16x8*)&Bs[br * 64 + ((pg ^ (br & 7)) << 3)];
            }
            #pragma unroll
            for (int m = 0; m < 4; m++)
                #pragma unroll
                for (int n = 0; n < 4; n++)
                    acc[m][n] = __builtin_amdgcn_mfma_f32_16x16x32_bf16(af[m], bf[n], acc[m][n], 0, 0, 0);
        }
        __syncthreads();
    }
    #pragma unroll
    for (int m = 0; m < 4; m++) {
        int rbase = wr * 64 + m * 16 + l4 * 4;
        #pragma unroll
        for (int n = 0; n < 4; n++) {
            int col = nb + wc * 64 + n * 16 + l15;
            float bv = bb[col];
            #pragma unroll
            for (int i = 0; i < 4; i++) {
                int r = rbase + i;
                if (r < acount) {
                    atomicAdd(out + (size_t)rows[r] * DD + col, wts[r] * (acc[m][n][i] + bv));
                }
            }
        }
    }
}

extern "C" void kernel_launch(void* const* d_in, const int* in_sizes, int n_in,
                              void* d_out, int out_size, void* d_ws, size_t ws_size,
                              hipStream_t stream)
{
    const float* x    = (const float*)d_in[0];
    const float* gW   = (const float*)d_in[1];
    const float* gb   = (const float*)d_in[2];
    const float* bias = (const float*)d_in[3];
    const float* W1   = (const float*)d_in[4];
    const float* b1   = (const float*)d_in[5];
    const float* W2   = (const float*)d_in[6];
    const float* b2   = (const float*)d_in[7];
    const float* sW1  = (const float*)d_in[8];
    const float* sb1  = (const float*)d_in[9];
    const float* sW2  = (const float*)d_in[10];
    const float* sb2  = (const float*)d_in[11];
    float* out = (float*)d_out;
    float* wsf = (float*)d_ws;
    int*   wsi = (int*)d_ws;

    hipMemsetAsync(d_out, 0, (size_t)out_size * sizeof(float), stream);
    hipMemsetAsync(d_ws, 0, 2048, stream);   // curs

    int*   curs   = wsi + WS_CURS;
    int*   counts = wsi + WS_COUNTS;
    float* Psum   = wsf + WS_PSUM;
    int*   offs   = wsi + WS_OFFS;
    int*   toffs  = wsi + WS_TOFFS;
    int*   total  = wsi + WS_TOTAL;
    int*   tokE   = wsi + WS_TOKE;
    float* tokW   = wsf + WS_TOKW;
    int*   ltok   = wsi + WS_LTOK;
    float* lwt    = wsf + WS_LW;
    float* Ppart  = wsf + WS_PPART;
    int*   Cpart  = wsi + WS_CPART;
    unsigned short* xb  = (unsigned short*)((char*)d_ws + XB_OFF);
    unsigned short* Hb  = (unsigned short*)((char*)d_ws + H_OFF);
    unsigned short* W1b = (unsigned short*)((char*)d_ws + W1B_OFF);
    unsigned short* W2b = (unsigned short*)((char*)d_ws + W2B_OFF);

    k_cvt_x<<<TT * DD / 4096, 256, 0, stream>>>(x, xb);
    k_cvt_w<<<dim3(HH / 64, DD / 64, NG), 256, 0, stream>>>(W1, sW1, DD, HH, W1b);
    k_cvt_w<<<dim3(DD / 64, HH / 64, NG), 256, 0, stream>>>(W2, sW2, HH, DD, W2b);
    k_gate<<<TT / 4, 256, 0, stream>>>(x, gW, gb, bias, tokE, tokW, Ppart, Cpart);
    k_reduce<<<NE, 256, 0, stream>>>(Ppart, Cpart, counts, Psum);
    k_scan<<<1, 64, 0, stream>>>(counts, Psum, offs, toffs, total, out + (size_t)TT * DD);
    k_scatter<<<TT / 256, 256, 0, stream>>>(tokE, tokW, offs, curs, ltok, lwt);
    k_mm1<<<NWG1, 256, 0, stream>>>(xb, W1b, b1, sb1, toffs, offs, total, ltok, Hb);
    k_mm2<<<NWG2, 256, 0, stream>>>(Hb, W2b, b2, sb2, toffs, offs, total, ltok, lwt, out);
}